// Round 5
// baseline (155.014 us; speedup 1.0000x reference)
//
#include <hip/hip_runtime.h>

// CostConcatenation: out[b, dd, h, w, :] = valid ? concat(left[b,h,w,:], right[b,h,w-d,:]) : 0
//   d = dd - 48, valid iff 0 <= w-d < 256 (both halves zeroed when invalid).
// left/right [2,64,256,32] f32; out [2,96,64,256,64] f32 (805 MB written once).
//
// R5: write BW was 5.4 TB/s vs 6.8 for pure-store fill. Changes:
//  - NONTEMPORAL stores: no L2 write-allocate -> input rows stay cached, write
//    stream doesn't mix with read turnarounds.
//  - Padded right row in LDS (idx in [w0-48, w0+176), zeros outside [0,256)):
//    right lanes are validity-logic-free; left lanes use ONE address cndmask to
//    an always-zero LDS slot. Store sources ds_read directly (no data cndmasks).
//  - Block = (hb, w-half, dd-half): 512 blocks, LDS 45184 B (< 64 KB static cap),
//    32 KB contiguous NT writes per k step.

typedef float f4 __attribute__((ext_vector_type(4)));

#define DD_STRIDE 262144   // f4 per disparity slice (64*256*16)

__global__ __launch_bounds__(256) void cost_concat_kernel(
    const f4* __restrict__ left4,
    const f4* __restrict__ right4,
    f4* __restrict__ out4)
{
    __shared__ f4 lds[2824];   // [0,1024) left half-row | [1024,2816) padded right | [2816,2824) zero slot

    const int t   = threadIdx.x;
    const int bid = blockIdx.x;            // 512 = hb(128) * wh(2) * g(2)
    const int g   = bid & 1;               // dd half: dd in [g*48, g*48+48)
    const int wh  = (bid >> 1) & 1;        // w half
    const int hb  = bid >> 2;              // b*64 + h
    const int w0  = wh << 7;
    const int dd0 = g * 48;
    const int rowBase = hb * 2048;         // f4 base of input row (256 w * 8 f4)

    // ---- stage left half-row: lds f4 [0,1024) = left[b,h, w0..w0+128) ----
    #pragma unroll
    for (int k = 0; k < 4; ++k)
        lds[k * 256 + t] = left4[rowBase + w0 * 8 + k * 256 + t];

    // ---- stage padded right: 224 pixels, idx in [w0-48, w0+176), zeros outside [0,256) ----
    #pragma unroll
    for (int k = 0; k < 7; ++k) {
        const int q = k * 256 + t;         // [0, 1792)
        const int idxPix = (w0 - 48) + (q >> 3);
        f4 v = (f4){0.f, 0.f, 0.f, 0.f};
        if ((unsigned)idxPix < 256u)
            v = right4[rowBase + idxPix * 8 + (q & 7)];
        lds[1024 + q] = v;
    }
    if (t < 8) lds[2816 + t] = (f4){0.f, 0.f, 0.f, 0.f};
    __syncthreads();

    const int c4 = t & 15;                 // f4 within 64-channel pixel
    const int wb = t >> 4;                 // pixel within 16-pixel granule
    const int cc = c4 & 7;
    const bool isLeft = c4 < 8;

    // LDS byte addressing for the hot loop (uniform code, no data selects):
    //   left lane (valid): (j*16+wb)*128 + cc*16            (k-independent)
    //   right lane:        16384 + p*128 + cc*16, p = wb - dd0 + 96 - k + j*16
    //   invalid (either):  Z (always-zero slot)
    const int Z = 2816 * 16;
    int addrB = isLeft ? (wb * 128 + cc * 16)
                       : (16384 + (wb - dd0 + 96) * 128 + cc * 16);
    const int dec = isLeft ? 0 : 128;      // per-k address decrement
    int ib = w0 + wb + 48 - dd0;           // idx at (k=0, j=0); per k: -1, per j: +16

    const int b = hb >> 6, h = hb & 63;
    f4* op = out4 + (size_t)b * 25165824 + (size_t)dd0 * DD_STRIDE
                  + (size_t)h * 4096 + (size_t)(w0 * 16) + t;

    const char* ldsb = (const char*)lds;

    for (int k = 0; k < 48; ++k) {
        #pragma unroll
        for (int j = 0; j < 8; ++j) {
            const int idxj = ib + j * 16;
            const int aj   = addrB + j * 2048;
            const int sel  = ((unsigned)idxj < 256u) ? aj : Z;
            f4 v = *(const f4*)(ldsb + sel);
            __builtin_nontemporal_store(v, op + j * 256);
        }
        ib -= 1; addrB -= dec; op += DD_STRIDE;
    }
}

extern "C" void kernel_launch(void* const* d_in, const int* in_sizes, int n_in,
                              void* d_out, int out_size, void* d_ws, size_t ws_size,
                              hipStream_t stream) {
    const f4* left4  = (const f4*)d_in[0];
    const f4* right4 = (const f4*)d_in[1];
    f4* out4 = (f4*)d_out;

    cost_concat_kernel<<<512, 256, 0, stream>>>(left4, right4, out4);
}

// Round 6
// 153.685 us; speedup vs baseline: 1.0087x; 1.0087x over previous
//
#include <hip/hip_runtime.h>

// CostConcatenation: out[b, dd, h, w, :] = valid ? concat(left[b,h,w,:], right[b,h,w-d,:]) : 0
//   d = dd - 48, valid iff 0 <= w-d < 256 (both halves zeroed when invalid).
// left/right [2,64,256,32] f32; out [2,96,64,256,64] f32 (805 MB written once).
//
// R6 = R4 (best, 149us) + staging-latency hiding:
//  1) issue the 16 staging loads into registers,
//  2) store the block's ZERO WEDGE (fully-invalid w-granules per dd) while the
//     loads are in flight -- keeps the store pipe busy during the only
//     unoverlapped phase R4 had,
//  3) ds_write + syncthreads,
//  4) main loop identical to R4 but skips the wedge granules (uniform branch).
// Write volume unchanged; zeros moved into the staging shadow. Plain stores
// (NT falsified in R5).

typedef float f4 __attribute__((ext_vector_type(4)));

#define DD_STRIDE 262144   // f4 per disparity slice (64*256*16)

__global__ __launch_bounds__(256) void cost_concat_kernel(
    const f4* __restrict__ left4,
    const f4* __restrict__ right4,
    f4* __restrict__ out4)
{
    __shared__ f4 lds[4096];           // [0,2048) left row | [2048,4096) right row

    const int t   = threadIdx.x;
    const int blk = blockIdx.x;        // 0..511
    const int g   = blk & 3;           // dd group: dd in [g*24, g*24+24)
    const int hb  = blk >> 2;          // b*64 + h
    const int rowBase = hb * 2048;     // f4 base of input row (256 w * 8 f4)
    const int dd0 = g * 24;
    const int b = hb >> 6, h = hb & 63;

    f4* orow = out4 + (size_t)b * 25165824 + (size_t)dd0 * DD_STRIDE + (size_t)h * 4096;

    // ---- 1) issue staging loads (coalesced) into registers ----
    f4 tL[8], tR[8];
    #pragma unroll
    for (int k = 0; k < 8; ++k) tL[k] = left4[rowBase + k * 256 + t];
    #pragma unroll
    for (int k = 0; k < 8; ++k) tR[k] = right4[rowBase + k * 256 + t];

    // ---- 2) zero-wedge stores: no deps, overlap the staging latency ----
    // granule j (16 pixels) of slice k is fully invalid iff j < jA or j > jB,
    // where valid w range = [max(0,d), 256+min(0,d)), d = dd0+k-48.
    const f4 z = (f4){0.f, 0.f, 0.f, 0.f};
    for (int k = 0; k < 24; ++k) {
        const int d = dd0 + k - 48;
        f4* op = orow + (size_t)k * DD_STRIDE + t;
        if (d > 0) {
            const int jA = d >> 4;                 // granules [0, jA) fully invalid
            for (int j = 0; j < jA; ++j) op[j * 256] = z;
        } else if (d < 0) {
            const int jB = ((271 + d) >> 4) - 1;   // granules (jB, 15] fully invalid
            for (int j = jB + 1; j < 16; ++j) op[j * 256] = z;
        }
    }

    // ---- 3) LDS writes + sync ----
    #pragma unroll
    for (int k = 0; k < 8; ++k) lds[k * 256 + t] = tL[k];
    #pragma unroll
    for (int k = 0; k < 8; ++k) lds[2048 + k * 256 + t] = tR[k];
    __syncthreads();

    const int c4 = t & 15;             // f4 within the 64-channel pixel
    const int wb = t >> 4;             // pixel within 16-pixel granule
    const int cc = c4 & 7;
    const bool isLeft = c4 < 8;

    // ---- 4) main loop: valid granules only (wedge already written) ----
    for (int k = 0; k < 24; ++k) {
        const int d = dd0 + k - 48;
        const int jA = (d > 0) ? (d >> 4) : 0;
        const int jB = (d < 0) ? (((271 + d) >> 4) - 1) : 15;
        f4* op = orow + (size_t)k * DD_STRIDE + t;
        #pragma unroll
        for (int j = 0; j < 16; ++j) {
            if (j < jA || j > jB) continue;        // uniform per-block branch
            const int w   = j * 16 + wb;
            const int idx = w - d;                 // right-image column
            const bool valid = (unsigned)idx < 256u;
            const int ci  = valid ? idx : 0;       // keep LDS addr in range
            const int la  = isLeft ? (w * 8 + cc) : (2048 + ci * 8 + cc);
            f4 v = lds[la];
            v = valid ? v : z;
            op[j * 256] = v;
        }
    }
}

extern "C" void kernel_launch(void* const* d_in, const int* in_sizes, int n_in,
                              void* d_out, int out_size, void* d_ws, size_t ws_size,
                              hipStream_t stream) {
    const f4* left4  = (const f4*)d_in[0];
    const f4* right4 = (const f4*)d_in[1];
    f4* out4 = (f4*)d_out;

    // 512 blocks = (hb 128) x (dd-group 4); 64 KB LDS -> 2 blocks/CU, all CUs busy.
    cost_concat_kernel<<<512, 256, 0, stream>>>(left4, right4, out4);
}